// Round 1
// baseline (460.319 us; speedup 1.0000x reference)
//
#include <hip/hip_runtime.h>

// Scatter: out[fault_idx[i]] = fault_vals[i]. Indices are unique (randperm),
// so plain stores are race-free.
__global__ void fi_scatter_kernel(const float* __restrict__ vals,
                                  const int* __restrict__ idx,
                                  float* __restrict__ out,
                                  int n) {
    int i = blockIdx.x * blockDim.x + threadIdx.x;
    if (i < n) {
        out[idx[i]] = vals[i];
    }
}

extern "C" void kernel_launch(void* const* d_in, const int* in_sizes, int n_in,
                              void* d_out, int out_size, void* d_ws, size_t ws_size,
                              hipStream_t stream) {
    const float* x     = (const float*)d_in[0];
    const float* vals  = (const float*)d_in[1];
    const int*   idx   = (const int*)d_in[2];
    float* out = (float*)d_out;

    const int numel = in_sizes[0];   // 67,108,864
    const int nf    = in_sizes[1];   // 671,089

    // 1) Bulk copy x -> out (256 MB) via driver D2D copy (graph-capture safe).
    hipMemcpyAsync(out, x, (size_t)numel * sizeof(float),
                   hipMemcpyDeviceToDevice, stream);

    // 2) Scatter the fault values over the copy (stream-ordered after the copy).
    const int block = 256;
    const int grid  = (nf + block - 1) / block;
    fi_scatter_kernel<<<grid, block, 0, stream>>>(vals, idx, out, nf);
}

// Round 2
// 450.421 us; speedup vs baseline: 1.0220x; 1.0220x over previous
//
#include <hip/hip_runtime.h>

// Vectorized 256 MB copy: one float4 (16 B) per thread, fully coalesced.
// m13-pattern: measured 6.29 TB/s on MI355X with this structure.
__global__ __launch_bounds__(256) void fi_copy_kernel(const float4* __restrict__ src,
                                                      float4* __restrict__ dst,
                                                      int n4) {
    int i = blockIdx.x * blockDim.x + threadIdx.x;
    if (i < n4) {
        dst[i] = src[i];
    }
}

// Scatter: out[fault_idx[i]] = fault_vals[i]. Indices are unique (randperm),
// so plain stores are race-free.
__global__ __launch_bounds__(256) void fi_scatter_kernel(const float* __restrict__ vals,
                                                         const int* __restrict__ idx,
                                                         float* __restrict__ out,
                                                         int n) {
    int i = blockIdx.x * blockDim.x + threadIdx.x;
    if (i < n) {
        out[idx[i]] = vals[i];
    }
}

extern "C" void kernel_launch(void* const* d_in, const int* in_sizes, int n_in,
                              void* d_out, int out_size, void* d_ws, size_t ws_size,
                              hipStream_t stream) {
    const float* x     = (const float*)d_in[0];
    const float* vals  = (const float*)d_in[1];
    const int*   idx   = (const int*)d_in[2];
    float* out = (float*)d_out;

    const int numel = in_sizes[0];   // 67,108,864 (divisible by 4)
    const int nf    = in_sizes[1];   // 671,089

    // 1) Bulk copy x -> out with float4 vector loads/stores.
    const int n4 = numel / 4;                     // 16,777,216
    const int cblock = 256;
    const int cgrid  = (n4 + cblock - 1) / cblock; // 65,536 blocks
    fi_copy_kernel<<<cgrid, cblock, 0, stream>>>((const float4*)x, (float4*)out, n4);

    // 2) Scatter the fault values over the copy (stream-ordered after the copy).
    const int block = 256;
    const int grid  = (nf + block - 1) / block;
    fi_scatter_kernel<<<grid, block, 0, stream>>>(vals, idx, out, nf);
}